// Round 1
// baseline (1224.671 us; speedup 1.0000x reference)
//
#include <hip/hip_runtime.h>

// Problem constants (from reference)
constexpr int NN   = 100000;    // nodes
constexpr int EE   = 6400000;   // directed edges
constexpr int FIN  = 128;
constexpr int HD   = 16;
constexpr int FOUT = 64;

// ---------------------------------------------------------------------------
// deg[v] = 1 (self-loop); then count in-degree over edges
// ---------------------------------------------------------------------------
__global__ __launch_bounds__(256) void init_deg_kernel(float* __restrict__ deg) {
    int v = blockIdx.x * 256 + threadIdx.x;
    if (v < NN) deg[v] = 1.0f;
}

__global__ __launch_bounds__(256) void count_deg_kernel(const int* __restrict__ dst,
                                                        float* __restrict__ deg) {
    int t = blockIdx.x * 256 + threadIdx.x;
    int base = t * 4;
    if (base + 3 < EE) {
        int4 d4 = *reinterpret_cast<const int4*>(dst + base);
        atomicAdd(&deg[d4.x], 1.0f);
        atomicAdd(&deg[d4.y], 1.0f);
        atomicAdd(&deg[d4.z], 1.0f);
        atomicAdd(&deg[d4.w], 1.0f);
    } else {
        for (int e = base; e < EE; ++e) atomicAdd(&deg[dst[e]], 1.0f);
    }
}

__global__ __launch_bounds__(256) void dinv_kernel(const float* __restrict__ deg,
                                                   float* __restrict__ dinv) {
    int v = blockIdx.x * 256 + threadIdx.x;
    if (v < NN) dinv[v] = rsqrtf(deg[v]);
}

// ---------------------------------------------------------------------------
// Layer-1 transform: t1[v,:] = (x[v,:] @ W1) * dinv[v];  agg1 init = t1 (self-loop)
// Block = 256 threads = 16 nodes x 16 hidden. W1 (8KB) + x tile (8.25KB) in LDS.
// ---------------------------------------------------------------------------
__global__ __launch_bounds__(256) void gemm1_kernel(const float* __restrict__ x,
                                                    const float* __restrict__ W1,
                                                    const float* __restrict__ dinv,
                                                    float* __restrict__ t1,
                                                    float* __restrict__ agg1) {
    __shared__ float W1s[FIN][HD];        // 128x16 = 8 KB
    __shared__ float xs[16][FIN + 1];     // +1 pad: avoids 4-way bank conflict on xs[r][k]
    int tid = threadIdx.x;
    int nodeBase = blockIdx.x * 16;

    for (int i = tid; i < FIN * HD; i += 256) W1s[i >> 4][i & 15] = W1[i];
    for (int i = tid; i < 16 * FIN; i += 256) {
        int r = i >> 7, c = i & 127;
        int v = nodeBase + r;
        xs[r][c] = (v < NN) ? x[(long long)v * FIN + c] : 0.0f;
    }
    __syncthreads();

    int r = tid >> 4;      // node within tile
    int j = tid & 15;      // hidden index
    int v = nodeBase + r;
    if (v < NN) {
        float acc = 0.0f;
        #pragma unroll
        for (int k = 0; k < FIN; ++k) acc += xs[r][k] * W1s[k][j];
        float val = acc * dinv[v];
        t1[v * HD + j] = val;
        agg1[v * HD + j] = val;   // self-loop contribution (dinv[v]^2 after post-scale)
    }
}

// ---------------------------------------------------------------------------
// Scatter-add over edges: agg[dst,:] += t[src,:]   (16 threads per edge)
// ---------------------------------------------------------------------------
__global__ __launch_bounds__(256) void scatter_kernel(const int* __restrict__ src,
                                                      const int* __restrict__ dst,
                                                      const float* __restrict__ t,
                                                      float* __restrict__ agg) {
    int idx = blockIdx.x * 256 + threadIdx.x;
    int e = idx >> 4;
    int j = idx & 15;
    if (e < EE) {
        int s = src[e];
        int d = dst[e];
        float val = t[s * HD + j];
        if (val != 0.0f) atomicAdd(&agg[d * HD + j], val);
    }
}

// ---------------------------------------------------------------------------
// Layer-1 epilogue fused with layer-2 pre-scale:
// t2[v,j] = relu(dinv[v]*agg1[v,j] + b1[j]) * dinv[v];  agg2 init = t2
// ---------------------------------------------------------------------------
__global__ __launch_bounds__(256) void fuse2_kernel(const float* __restrict__ agg1,
                                                    const float* __restrict__ dinv,
                                                    const float* __restrict__ b1,
                                                    float* __restrict__ t2,
                                                    float* __restrict__ agg2) {
    int idx = blockIdx.x * 256 + threadIdx.x;
    if (idx < NN * HD) {
        int v = idx >> 4, j = idx & 15;
        float di = dinv[v];
        float h = fmaxf(di * agg1[idx] + b1[j], 0.0f);
        float val = h * di;
        t2[idx] = val;
        agg2[idx] = val;
    }
}

// ---------------------------------------------------------------------------
// Layer-2 transform AFTER aggregation (linearity): out[v,:] = (dinv[v]*agg2[v,:]) @ W2 + b2
// Block = 256 threads = 4 nodes x 64 out. W2 (4KB) + 4 agg rows in LDS.
// ---------------------------------------------------------------------------
__global__ __launch_bounds__(256) void gemm2_kernel(const float* __restrict__ agg2,
                                                    const float* __restrict__ W2,
                                                    const float* __restrict__ dinv,
                                                    const float* __restrict__ b2,
                                                    float* __restrict__ out) {
    __shared__ float W2s[HD][FOUT];   // 16x64 = 4 KB
    __shared__ float as[4][HD];
    int tid = threadIdx.x;
    int nodeBase = blockIdx.x * 4;

    for (int i = tid; i < HD * FOUT; i += 256) W2s[i >> 6][i & 63] = W2[i];
    if (tid < 4 * HD) {
        int r = tid >> 4, k = tid & 15;
        int v = nodeBase + r;
        as[r][k] = (v < NN) ? agg2[v * HD + k] : 0.0f;
    }
    __syncthreads();

    int r = tid >> 6;    // node within tile (one wave per node)
    int j = tid & 63;    // output index
    int v = nodeBase + r;
    if (v < NN) {
        float acc = 0.0f;
        #pragma unroll
        for (int k = 0; k < HD; ++k) acc += as[r][k] * W2s[k][j];
        out[(long long)v * FOUT + j] = acc * dinv[v] + b2[j];
    }
}

// ---------------------------------------------------------------------------
extern "C" void kernel_launch(void* const* d_in, const int* in_sizes, int n_in,
                              void* d_out, int out_size, void* d_ws, size_t ws_size,
                              hipStream_t stream) {
    const float* x  = (const float*)d_in[0];
    const int*   ei = (const int*)d_in[1];      // [2, E] row-major
    const float* W1 = (const float*)d_in[2];
    const float* b1 = (const float*)d_in[3];
    const float* W2 = (const float*)d_in[4];
    const float* b2 = (const float*)d_in[5];
    float* out = (float*)d_out;

    const int* src = ei;
    const int* dst = ei + EE;

    float* ws   = (float*)d_ws;
    float* deg  = ws;                 // N
    float* dinv = ws + NN;            // N
    float* t1   = ws + 2 * NN;        // N*16
    float* agg1 = t1 + NN * HD;       // N*16
    float* t2   = agg1 + NN * HD;     // N*16
    float* agg2 = t2 + NN * HD;       // N*16

    init_deg_kernel<<<(NN + 255) / 256, 256, 0, stream>>>(deg);
    count_deg_kernel<<<(EE / 4 + 255) / 256, 256, 0, stream>>>(dst, deg);
    dinv_kernel<<<(NN + 255) / 256, 256, 0, stream>>>(deg, dinv);

    gemm1_kernel<<<(NN + 15) / 16, 256, 0, stream>>>(x, W1, dinv, t1, agg1);
    scatter_kernel<<<(EE * 16) / 256, 256, 0, stream>>>(src, dst, t1, agg1);
    fuse2_kernel<<<(NN * HD + 255) / 256, 256, 0, stream>>>(agg1, dinv, b1, t2, agg2);
    scatter_kernel<<<(EE * 16) / 256, 256, 0, stream>>>(src, dst, t2, agg2);
    gemm2_kernel<<<(NN + 3) / 4, 256, 0, stream>>>(agg2, W2, dinv, b2, out);
}

// Round 2
// 1123.392 us; speedup vs baseline: 1.0902x; 1.0902x over previous
//
#include <hip/hip_runtime.h>

// Problem constants (from reference)
constexpr int NN   = 100000;    // nodes
constexpr int EE   = 6400000;   // directed edges
constexpr int FIN  = 128;
constexpr int HD   = 16;
constexpr int FOUT = 64;
constexpr int SB   = 256;                         // scan block
constexpr int NBLK = (NN + SB - 1) / SB;          // 391

// ---------------------------------------------------------------------------
// CSR build: degree count (int), exclusive scan, cursor placement.
// ---------------------------------------------------------------------------
__global__ __launch_bounds__(256) void zero_deg_kernel(int* __restrict__ degi) {
    int v = blockIdx.x * 256 + threadIdx.x;
    if (v < NN) degi[v] = 0;
}

__global__ __launch_bounds__(256) void count_deg_kernel(const int* __restrict__ dst,
                                                        int* __restrict__ degi) {
    int t = blockIdx.x * 256 + threadIdx.x;
    int base = t * 4;
    if (base + 3 < EE) {
        int4 d4 = *reinterpret_cast<const int4*>(dst + base);
        atomicAdd(&degi[d4.x], 1);
        atomicAdd(&degi[d4.y], 1);
        atomicAdd(&degi[d4.z], 1);
        atomicAdd(&degi[d4.w], 1);
    } else {
        for (int e = base; e < EE; ++e) atomicAdd(&degi[dst[e]], 1);
    }
}

__global__ __launch_bounds__(256) void block_sum_kernel(const int* __restrict__ degi,
                                                        int* __restrict__ bsum) {
    __shared__ int s[SB];
    int tid = threadIdx.x;
    int v = blockIdx.x * SB + tid;
    s[tid] = (v < NN) ? degi[v] : 0;
    __syncthreads();
    for (int st = 128; st; st >>= 1) {
        if (tid < st) s[tid] += s[tid + st];
        __syncthreads();
    }
    if (tid == 0) bsum[blockIdx.x] = s[0];
}

__global__ __launch_bounds__(256) void scan_bsums_kernel(const int* __restrict__ bsum,
                                                         int* __restrict__ bofs) {
    __shared__ int s[NBLK];
    int tid = threadIdx.x;
    for (int i = tid; i < NBLK; i += 256) s[i] = bsum[i];
    __syncthreads();
    if (tid == 0) {
        int run = 0;
        for (int i = 0; i < NBLK; ++i) { int x = s[i]; s[i] = run; run += x; }
    }
    __syncthreads();
    for (int i = tid; i < NBLK; i += 256) bofs[i] = s[i];
}

// exclusive scan within block + block offset; also emit cursor copy and dinv
__global__ __launch_bounds__(256) void scan_finish_kernel(const int* __restrict__ degi,
                                                          const int* __restrict__ bofs,
                                                          int* __restrict__ rowptr,
                                                          int* __restrict__ cursor,
                                                          float* __restrict__ dinv) {
    __shared__ int s[SB];
    int tid = threadIdx.x;
    int v = blockIdx.x * SB + tid;
    int val = (v < NN) ? degi[v] : 0;
    s[tid] = val;
    __syncthreads();
    for (int st = 1; st < SB; st <<= 1) {   // Hillis-Steele inclusive scan
        int add = (tid >= st) ? s[tid - st] : 0;
        __syncthreads();
        s[tid] += add;
        __syncthreads();
    }
    if (v < NN) {
        int excl = s[tid] - val + bofs[blockIdx.x];
        rowptr[v] = excl;
        cursor[v] = excl;
        dinv[v]   = rsqrtf((float)(val + 1));   // +1 self-loop
    }
}

__global__ __launch_bounds__(256) void fill_csr_kernel(const int* __restrict__ src,
                                                       const int* __restrict__ dst,
                                                       int* __restrict__ cursor,
                                                       int* __restrict__ srcs) {
    int e = blockIdx.x * 256 + threadIdx.x;
    if (e < EE) {
        int pos = atomicAdd(&cursor[dst[e]], 1);
        srcs[pos] = src[e];
    }
}

// ---------------------------------------------------------------------------
// Layer-1 transform: t1[v,:] = (x[v,:] @ W1) * dinv[v]
// ---------------------------------------------------------------------------
__global__ __launch_bounds__(256) void gemm1_kernel(const float* __restrict__ x,
                                                    const float* __restrict__ W1,
                                                    const float* __restrict__ dinv,
                                                    float* __restrict__ t1) {
    __shared__ float W1s[FIN][HD];        // 8 KB
    __shared__ float xs[16][FIN + 1];     // pad breaks bank conflicts
    int tid = threadIdx.x;
    int nodeBase = blockIdx.x * 16;

    for (int i = tid; i < FIN * HD; i += 256) W1s[i >> 4][i & 15] = W1[i];
    for (int i = tid; i < 16 * FIN; i += 256) {
        int r = i >> 7, c = i & 127;
        int v = nodeBase + r;
        xs[r][c] = (v < NN) ? x[(long long)v * FIN + c] : 0.0f;
    }
    __syncthreads();

    int r = tid >> 4, j = tid & 15;
    int v = nodeBase + r;
    if (v < NN) {
        float acc = 0.0f;
        #pragma unroll
        for (int k = 0; k < FIN; ++k) acc += xs[r][k] * W1s[k][j];
        t1[v * HD + j] = acc * dinv[v];
    }
}

// ---------------------------------------------------------------------------
// Gather-aggregate: agg[v,:] = t[v,:] + sum_{e: dst=v} t[srcs[e],:]
// One 64-lane wave per node: 4 edge-subgroups x 16 feature lanes, unroll 4.
// No atomics — deterministic register accumulation.
// ---------------------------------------------------------------------------
__global__ __launch_bounds__(256) void gather_kernel(const int* __restrict__ rowptr,
                                                     const int* __restrict__ degi,
                                                     const int* __restrict__ srcs,
                                                     const float* __restrict__ t,
                                                     float* __restrict__ agg) {
    int gw = (blockIdx.x * 256 + threadIdx.x) >> 6;   // node = global wave id
    int lane = threadIdx.x & 63;
    if (gw >= NN) return;
    int start = rowptr[gw];
    int cnt   = degi[gw];
    int j   = lane & 15;
    int sub = lane >> 4;       // 0..3
    float acc = 0.0f;
    int e = sub;
    for (; e + 12 < cnt; e += 16) {      // 4-deep MLP: batch src loads, then t loads
        int s0 = srcs[start + e];
        int s1 = srcs[start + e + 4];
        int s2 = srcs[start + e + 8];
        int s3 = srcs[start + e + 12];
        float a0 = t[s0 * HD + j];
        float a1 = t[s1 * HD + j];
        float a2 = t[s2 * HD + j];
        float a3 = t[s3 * HD + j];
        acc += a0 + a1 + a2 + a3;
    }
    for (; e < cnt; e += 4) acc += t[srcs[start + e] * HD + j];
    acc += __shfl_xor(acc, 16);          // fold 4 subgroups
    acc += __shfl_xor(acc, 32);
    if (sub == 0) agg[gw * HD + j] = acc + t[gw * HD + j];  // + self-loop
}

// ---------------------------------------------------------------------------
// Layer-1 epilogue + layer-2 pre-scale: t2 = relu(dinv*agg1 + b1) * dinv
// ---------------------------------------------------------------------------
__global__ __launch_bounds__(256) void fuse2_kernel(const float* __restrict__ agg1,
                                                    const float* __restrict__ dinv,
                                                    const float* __restrict__ b1,
                                                    float* __restrict__ t2) {
    int idx = blockIdx.x * 256 + threadIdx.x;
    if (idx < NN * HD) {
        int v = idx >> 4, j = idx & 15;
        float di = dinv[v];
        float h = fmaxf(di * agg1[idx] + b1[j], 0.0f);
        t2[idx] = h * di;
    }
}

// ---------------------------------------------------------------------------
// Layer-2 transform AFTER aggregation: out[v,:] = (dinv[v]*agg2[v,:]) @ W2 + b2
// ---------------------------------------------------------------------------
__global__ __launch_bounds__(256) void gemm2_kernel(const float* __restrict__ agg2,
                                                    const float* __restrict__ W2,
                                                    const float* __restrict__ dinv,
                                                    const float* __restrict__ b2,
                                                    float* __restrict__ out) {
    __shared__ float W2s[HD][FOUT];   // 4 KB
    __shared__ float as[4][HD];
    int tid = threadIdx.x;
    int nodeBase = blockIdx.x * 4;

    for (int i = tid; i < HD * FOUT; i += 256) W2s[i >> 6][i & 63] = W2[i];
    if (tid < 4 * HD) {
        int r = tid >> 4, k = tid & 15;
        int v = nodeBase + r;
        as[r][k] = (v < NN) ? agg2[v * HD + k] : 0.0f;
    }
    __syncthreads();

    int r = tid >> 6, j = tid & 63;
    int v = nodeBase + r;
    if (v < NN) {
        float acc = 0.0f;
        #pragma unroll
        for (int k = 0; k < HD; ++k) acc += as[r][k] * W2s[k][j];
        out[(long long)v * FOUT + j] = acc * dinv[v] + b2[j];
    }
}

// ---------------------------------------------------------------------------
extern "C" void kernel_launch(void* const* d_in, const int* in_sizes, int n_in,
                              void* d_out, int out_size, void* d_ws, size_t ws_size,
                              hipStream_t stream) {
    const float* x  = (const float*)d_in[0];
    const int*   ei = (const int*)d_in[1];      // [2, E] row-major
    const float* W1 = (const float*)d_in[2];
    const float* b1 = (const float*)d_in[3];
    const float* W2 = (const float*)d_in[4];
    const float* b2 = (const float*)d_in[5];
    float* out = (float*)d_out;

    const int* src = ei;
    const int* dst = ei + EE;

    // workspace layout (~40 MB)
    int* wsI    = (int*)d_ws;
    int* degi   = wsI;                 // N
    int* rowptr = wsI + NN;            // N
    int* cursor = wsI + 2 * NN;        // N
    int* bsum   = wsI + 3 * NN;        // NBLK (pad 512)
    int* bofs   = bsum + 512;          // NBLK (pad 512)
    int* srcs   = bofs + 512;          // E
    float* dinv = (float*)(srcs + EE); // N
    float* t1   = dinv + NN;           // N*HD
    float* agg1 = t1 + NN * HD;        // N*HD
    float* t2   = t1;                  // alias: t1 dead after gather1
    float* agg2 = agg1;                // alias: agg1 dead after fuse2

    // CSR build
    zero_deg_kernel<<<(NN + 255) / 256, 256, 0, stream>>>(degi);
    count_deg_kernel<<<(EE / 4 + 255) / 256, 256, 0, stream>>>(dst, degi);
    block_sum_kernel<<<NBLK, SB, 0, stream>>>(degi, bsum);
    scan_bsums_kernel<<<1, 256, 0, stream>>>(bsum, bofs);
    scan_finish_kernel<<<NBLK, SB, 0, stream>>>(degi, bofs, rowptr, cursor, dinv);
    fill_csr_kernel<<<(EE + 255) / 256, 256, 0, stream>>>(src, dst, cursor, srcs);

    // layer 1
    gemm1_kernel<<<(NN + 15) / 16, 256, 0, stream>>>(x, W1, dinv, t1);
    gather_kernel<<<(NN + 3) / 4, 256, 0, stream>>>(rowptr, degi, srcs, t1, agg1);
    fuse2_kernel<<<(NN * HD + 255) / 256, 256, 0, stream>>>(agg1, dinv, b1, t2);
    // layer 2 (aggregate in hidden dim, transform after)
    gather_kernel<<<(NN + 3) / 4, 256, 0, stream>>>(rowptr, degi, srcs, t2, agg2);
    gemm2_kernel<<<(NN + 3) / 4, 256, 0, stream>>>(agg2, W2, dinv, b2, out);
}

// Round 4
// 512.642 us; speedup vs baseline: 2.3889x; 2.1914x over previous
//
#include <hip/hip_runtime.h>

// Problem constants (from reference)
constexpr int NN   = 100000;    // nodes
constexpr int EE   = 6400000;   // directed edges
constexpr int FIN  = 128;
constexpr int HD   = 16;
constexpr int FOUT = 64;

// Two-level counting sort parameters
constexpr int CB     = 9;                          // coarse shift: bucket = dst >> 9
constexpr int BUKN   = 1 << CB;                    // 512 nodes per bucket
constexpr int NBUK   = (NN + BUKN - 1) >> CB;      // 196 buckets
constexpr int CHUNK  = 4096;                       // edges per WG in coarse scatter
constexpr int NCHUNK = (EE + CHUNK - 1) / CHUNK;   // 1563

// ---------------------------------------------------------------------------
__global__ __launch_bounds__(256) void zero_chist_kernel(int* __restrict__ chist) {
    chist[threadIdx.x] = 0;     // 256 entries (NBUK=196 used)
}

// Coarse histogram over dst>>CB, LDS-staged
__global__ __launch_bounds__(256) void coarse_hist_kernel(const int* __restrict__ dst,
                                                          int* __restrict__ chist) {
    __shared__ int h[256];
    int tid = threadIdx.x;
    h[tid] = 0;
    __syncthreads();
    int stride = gridDim.x * 256;
    for (int i = blockIdx.x * 256 + tid; i < EE / 4; i += stride) {
        int4 d4 = reinterpret_cast<const int4*>(dst)[i];
        atomicAdd(&h[d4.x >> CB], 1);
        atomicAdd(&h[d4.y >> CB], 1);
        atomicAdd(&h[d4.z >> CB], 1);
        atomicAdd(&h[d4.w >> CB], 1);
    }
    __syncthreads();
    if (h[tid]) atomicAdd(&chist[tid], h[tid]);
}

// Exclusive scan of 256 coarse bins -> cofs[257]; bcur = working cursors
__global__ __launch_bounds__(256) void scan_coarse_kernel(const int* __restrict__ chist,
                                                          int* __restrict__ cofs,
                                                          int* __restrict__ bcur) {
    __shared__ int s[256];
    int tid = threadIdx.x;
    int val = chist[tid];
    s[tid] = val;
    __syncthreads();
    for (int st = 1; st < 256; st <<= 1) {
        int add = (tid >= st) ? s[tid - st] : 0;
        __syncthreads();
        s[tid] += add;
        __syncthreads();
    }
    int excl = s[tid] - val;
    cofs[tid] = excl;
    bcur[tid] = excl;
    if (tid == 255) cofs[256] = s[255];
}

// Coarse scatter: rank chunk's edges by bucket in LDS, claim global bases,
// write packed (dstLow<<20 | src) u32s in coalesced per-bucket runs.
__global__ __launch_bounds__(256) void coarse_scatter_kernel(const int* __restrict__ src,
                                                             const int* __restrict__ dst,
                                                             int* __restrict__ bcur,
                                                             unsigned int* __restrict__ pair) {
    __shared__ int h[256];
    __shared__ int exc[256];
    __shared__ int cur[256];
    __shared__ int gbase[256];
    __shared__ unsigned int stage[CHUNK];       // 16 KB
    __shared__ unsigned char binOf[CHUNK];      // 4 KB
    int tid = threadIdx.x;
    int e0 = blockIdx.x * CHUNK;
    int n = min(CHUNK, EE - e0);

    h[tid] = 0;
    __syncthreads();
    for (int i = tid; i < n; i += 256) atomicAdd(&h[dst[e0 + i] >> CB], 1);
    __syncthreads();
    // exclusive scan of h -> exc
    {
        int val = h[tid];
        exc[tid] = val;
        __syncthreads();
        for (int st = 1; st < 256; st <<= 1) {
            int add = (tid >= st) ? exc[tid - st] : 0;
            __syncthreads();
            exc[tid] += add;
            __syncthreads();
        }
        exc[tid] -= val;
    }
    cur[tid] = exc[tid];
    gbase[tid] = atomicAdd(&bcur[tid], h[tid]);   // per-bucket global base (few, low-contention)
    __syncthreads();
    // rank & stage
    for (int i = tid; i < n; i += 256) {
        int d = dst[e0 + i];
        int s = src[e0 + i];
        int b = d >> CB;
        int p = atomicAdd(&cur[b], 1);
        stage[p] = (unsigned int)s | ((unsigned int)(d & (BUKN - 1)) << 20);
        binOf[p] = (unsigned char)b;
    }
    __syncthreads();
    // coalesced write-out per bucket run
    for (int i = tid; i < n; i += 256) {
        int b = binOf[i];
        pair[gbase[b] + (i - exc[b])] = stage[i];
    }
}

// Per-bucket CSR build: histogram 512 local bins, scan, emit rowptr/deg/dinv,
// place srcs within the bucket's contiguous (L2-local) window.
__global__ __launch_bounds__(256) void bucket_build_kernel(const unsigned int* __restrict__ pair,
                                                           const int* __restrict__ cofs,
                                                           int* __restrict__ rowptr,
                                                           int* __restrict__ degi,
                                                           float* __restrict__ dinv,
                                                           int* __restrict__ srcs) {
    __shared__ int h[BUKN];
    __shared__ int ofs[BUKN];
    __shared__ int cur[BUKN];
    __shared__ int ps[256];
    int tid = threadIdx.x;
    int b = blockIdx.x;
    int lo = cofs[b], hi = cofs[b + 1];

    h[tid] = 0; h[tid + 256] = 0;
    __syncthreads();
    for (int i = lo + tid; i < hi; i += 256)
        atomicAdd(&h[pair[i] >> 20], 1);
    __syncthreads();
    // scan 512 bins: 2 per thread
    int a0 = h[2 * tid], a1 = h[2 * tid + 1];
    int pssum = a0 + a1;
    ps[tid] = pssum;
    __syncthreads();
    for (int st = 1; st < 256; st <<= 1) {
        int add = (tid >= st) ? ps[tid - st] : 0;
        __syncthreads();
        ps[tid] += add;
        __syncthreads();
    }
    int exclp = ps[tid] - pssum;
    ofs[2 * tid] = exclp;
    ofs[2 * tid + 1] = exclp + a0;
    __syncthreads();
    // node outputs + cursors
    int v0 = b << CB;
    for (int k = tid; k < BUKN; k += 256) {
        int v = v0 + k;
        cur[k] = lo + ofs[k];
        if (v < NN) {
            rowptr[v] = lo + ofs[k];
            degi[v]   = h[k];
            dinv[v]   = rsqrtf((float)(h[k] + 1));
        }
    }
    __syncthreads();
    // place
    for (int i = lo + tid; i < hi; i += 256) {
        unsigned int pd = pair[i];
        int p = atomicAdd(&cur[pd >> 20], 1);
        srcs[p] = (int)(pd & 0xFFFFFu);
    }
}

// ---------------------------------------------------------------------------
// Layer-1 transform: t1[v,:] = (x[v,:] @ W1) * dinv[v]
// ---------------------------------------------------------------------------
__global__ __launch_bounds__(256) void gemm1_kernel(const float* __restrict__ x,
                                                    const float* __restrict__ W1,
                                                    const float* __restrict__ dinv,
                                                    float* __restrict__ t1) {
    __shared__ float W1s[FIN][HD];        // 8 KB
    __shared__ float xs[16][FIN + 1];     // pad breaks bank conflicts
    int tid = threadIdx.x;
    int nodeBase = blockIdx.x * 16;

    for (int i = tid; i < FIN * HD; i += 256) W1s[i >> 4][i & 15] = W1[i];
    for (int i = tid; i < 16 * FIN; i += 256) {
        int r = i >> 7, c = i & 127;
        int v = nodeBase + r;
        xs[r][c] = (v < NN) ? x[(long long)v * FIN + c] : 0.0f;
    }
    __syncthreads();

    int r = tid >> 4, j = tid & 15;
    int v = nodeBase + r;
    if (v < NN) {
        float acc = 0.0f;
        #pragma unroll
        for (int k = 0; k < FIN; ++k) acc += xs[r][k] * W1s[k][j];
        t1[v * HD + j] = acc * dinv[v];
    }
}

// ---------------------------------------------------------------------------
// Gather-aggregate: agg[v,:] = t[v,:] + sum_{e: dst=v} t[srcs[e],:]
// One 64-lane wave per node: 4 edge-subgroups x 16 feature lanes, unroll 4.
// ---------------------------------------------------------------------------
__global__ __launch_bounds__(256) void gather_kernel(const int* __restrict__ rowptr,
                                                     const int* __restrict__ degi,
                                                     const int* __restrict__ srcs,
                                                     const float* __restrict__ t,
                                                     float* __restrict__ agg) {
    int gw = (blockIdx.x * 256 + threadIdx.x) >> 6;   // node = global wave id
    int lane = threadIdx.x & 63;
    if (gw >= NN) return;
    int start = rowptr[gw];
    int cnt   = degi[gw];
    int j   = lane & 15;
    int sub = lane >> 4;       // 0..3
    float acc = 0.0f;
    int e = sub;
    for (; e + 12 < cnt; e += 16) {      // 4-deep MLP
        int s0 = srcs[start + e];
        int s1 = srcs[start + e + 4];
        int s2 = srcs[start + e + 8];
        int s3 = srcs[start + e + 12];
        float a0 = t[s0 * HD + j];
        float a1 = t[s1 * HD + j];
        float a2 = t[s2 * HD + j];
        float a3 = t[s3 * HD + j];
        acc += a0 + a1 + a2 + a3;
    }
    for (; e < cnt; e += 4) acc += t[srcs[start + e] * HD + j];
    acc += __shfl_xor(acc, 16);
    acc += __shfl_xor(acc, 32);
    if (sub == 0) agg[gw * HD + j] = acc + t[gw * HD + j];  // + self-loop
}

// ---------------------------------------------------------------------------
// Layer-1 epilogue + layer-2 pre-scale: t2 = relu(dinv*agg1 + b1) * dinv
// ---------------------------------------------------------------------------
__global__ __launch_bounds__(256) void fuse2_kernel(const float* __restrict__ agg1,
                                                    const float* __restrict__ dinv,
                                                    const float* __restrict__ b1,
                                                    float* __restrict__ t2) {
    int idx = blockIdx.x * 256 + threadIdx.x;
    if (idx < NN * HD) {
        int v = idx >> 4, j = idx & 15;
        float di = dinv[v];
        float h = fmaxf(di * agg1[idx] + b1[j], 0.0f);
        t2[idx] = h * di;
    }
}

// ---------------------------------------------------------------------------
// Layer-2 transform AFTER aggregation: out[v,:] = (dinv[v]*agg2[v,:]) @ W2 + b2
// ---------------------------------------------------------------------------
__global__ __launch_bounds__(256) void gemm2_kernel(const float* __restrict__ agg2,
                                                    const float* __restrict__ W2,
                                                    const float* __restrict__ dinv,
                                                    const float* __restrict__ b2,
                                                    float* __restrict__ out) {
    __shared__ float W2s[HD][FOUT];   // 4 KB
    __shared__ float as[4][HD];
    int tid = threadIdx.x;
    int nodeBase = blockIdx.x * 4;

    for (int i = tid; i < HD * FOUT; i += 256) W2s[i >> 6][i & 63] = W2[i];
    if (tid < 4 * HD) {
        int r = tid >> 4, k = tid & 15;
        int v = nodeBase + r;
        as[r][k] = (v < NN) ? agg2[v * HD + k] : 0.0f;
    }
    __syncthreads();

    int r = tid >> 6, j = tid & 63;
    int v = nodeBase + r;
    if (v < NN) {
        float acc = 0.0f;
        #pragma unroll
        for (int k = 0; k < HD; ++k) acc += as[r][k] * W2s[k][j];
        out[(long long)v * FOUT + j] = acc * dinv[v] + b2[j];
    }
}

// ---------------------------------------------------------------------------
extern "C" void kernel_launch(void* const* d_in, const int* in_sizes, int n_in,
                              void* d_out, int out_size, void* d_ws, size_t ws_size,
                              hipStream_t stream) {
    const float* x  = (const float*)d_in[0];
    const int*   ei = (const int*)d_in[1];      // [2, E] row-major
    const float* W1 = (const float*)d_in[2];
    const float* b1 = (const float*)d_in[3];
    const float* W2 = (const float*)d_in[4];
    const float* b2 = (const float*)d_in[5];
    float* out = (float*)d_out;

    const int* src = ei;
    const int* dst = ei + EE;

    // workspace layout (~62 MB)
    int* wsI    = (int*)d_ws;
    int* chist  = wsI;                     // 256
    int* cofs   = chist + 256;             // 257 (pad 512)
    int* bcur   = cofs + 512;              // 256
    int* rowptr = bcur + 256;              // N
    int* degi   = rowptr + NN;             // N
    float* dinv = (float*)(degi + NN);     // N
    unsigned int* pair = (unsigned int*)(dinv + NN);  // E
    int* srcs   = (int*)(pair + EE);       // E
    float* t1   = (float*)(srcs + EE);     // N*HD
    float* agg1 = t1 + NN * HD;            // N*HD
    float* t2   = t1;                      // alias: t1 dead after gather1
    float* agg2 = agg1;                    // alias: agg1 dead after fuse2

    // CSR build via two-level counting sort (no f32 atomics, few returning atomics)
    zero_chist_kernel<<<1, 256, 0, stream>>>(chist);
    coarse_hist_kernel<<<1024, 256, 0, stream>>>(dst, chist);
    scan_coarse_kernel<<<1, 256, 0, stream>>>(chist, cofs, bcur);
    coarse_scatter_kernel<<<NCHUNK, 256, 0, stream>>>(src, dst, bcur, pair);
    bucket_build_kernel<<<NBUK, 256, 0, stream>>>(pair, cofs, rowptr, degi, dinv, srcs);

    // layer 1
    gemm1_kernel<<<(NN + 15) / 16, 256, 0, stream>>>(x, W1, dinv, t1);
    gather_kernel<<<(NN + 3) / 4, 256, 0, stream>>>(rowptr, degi, srcs, t1, agg1);
    fuse2_kernel<<<(NN * HD + 255) / 256, 256, 0, stream>>>(agg1, dinv, b1, t2);
    // layer 2 (aggregate in hidden dim, transform after)
    gather_kernel<<<(NN + 3) / 4, 256, 0, stream>>>(rowptr, degi, srcs, t2, agg2);
    gemm2_kernel<<<(NN + 3) / 4, 256, 0, stream>>>(agg2, W2, dinv, b2, out);
}